// Round 10
// baseline (608.615 us; speedup 1.0000x reference)
//
#include <hip/hip_runtime.h>
#include <cstddef>
#include <cstdint>

typedef __attribute__((ext_vector_type(8))) short short8;
typedef __attribute__((ext_vector_type(4))) float float4v;
typedef __attribute__((ext_vector_type(2))) float float2v;
typedef __attribute__((ext_vector_type(2))) __bf16 bf162;

// ---------------------------------------------------------------- bf16 helpers
__device__ __forceinline__ float bf2f_lo(unsigned int u) {
    union { unsigned int i; float f; } v; v.i = u << 16; return v.f;
}
__device__ __forceinline__ float bf2f_hi(unsigned int u) {
    union { unsigned int i; float f; } v; v.i = u & 0xFFFF0000u; return v.f;
}
__device__ __forceinline__ unsigned short f2bf(float f) {
    union { float f; unsigned int i; } v; v.f = f;
    unsigned int x = v.i;
    unsigned int r = (x + 0x7FFFu + ((x >> 16) & 1u)) >> 16;
    return (unsigned short)r;
}
__device__ __forceinline__ unsigned int pk2(float lo, float hi) {
    return (unsigned int)f2bf(lo) | ((unsigned int)f2bf(hi) << 16);
}
__device__ __forceinline__ float geluf(float x) {
    return 0.5f * x * (1.0f + erff(x * 0.70710678118654752f));
}
__device__ __forceinline__ float dot2bf(unsigned int a, unsigned int b, float c) {
#if defined(__has_builtin) && __has_builtin(__builtin_amdgcn_fdot2_f32_bf16)
    union U { unsigned int u; bf162 v; };
    U ua, ub; ua.u = a; ub.u = b;
    return __builtin_amdgcn_fdot2_f32_bf16(ua.v, ub.v, c, false);
#else
    return c + bf2f_lo(a) * bf2f_lo(b) + bf2f_hi(a) * bf2f_hi(b);
#endif
}
__device__ __forceinline__ unsigned int gate_pack(unsigned int nu, unsigned int ou,
                                                  float2v g2, float2v og2) {
    float2v n = {bf2f_lo(nu), bf2f_hi(nu)};
    float2v o = {bf2f_lo(ou), bf2f_hi(ou)};
    float2v r = n * g2 + o * og2;
    return pk2(r.x, r.y);
}

// ---------------------------------------------------------------- zero fill
__global__ void k_zero(int* __restrict__ p, int n) {
    int i = blockIdx.x * 256 + threadIdx.x;
    if (i < n) p[i] = 0;
}

// ---------------------------------------------------------------- swizzle weights into MFMA B-fragment order (bf16), 25 units
__global__ void k_swz(const float* __restrict__ mlp_in_w, const float* __restrict__ q_w,
                      const float* __restrict__ a_w, const float* __restrict__ mow0,
                      const float* __restrict__ mow1, const float* __restrict__ mow2,
                      const float* __restrict__ kw, const float* __restrict__ kb,
                      const float* __restrict__ vw, const float* __restrict__ vb,
                      const float* __restrict__ arel, const float* __restrict__ mrel,
                      const float* __restrict__ prel,
                      unsigned short* __restrict__ Wswz, float* __restrict__ Bkv) {
    int idx = blockIdx.y;
    int f = blockIdx.x * 256 + threadIdx.x;
    if (idx == 25) {                      // bias fold for k'/v'
        if (f >= 1024) return;
        int lt = f >> 8, c = f & 255;
        int sec = c >> 7, cc = c & 127, h = cc >> 5, e = cc & 31;
        const float* B = sec ? vb : kb;
        const float* R = sec ? mrel : arel;
        float scale = sec ? 1.f : prel[lt * 4 + h] * 0.17677669529663687f;
        const float* rp = R + (size_t)(lt * 4 + h) * 1024 + e;
        const float* bp = B + lt * 128 + h * 32;
        float s = 0.f;
        #pragma unroll 8
        for (int d = 0; d < 32; ++d) s += bp[d] * rp[(size_t)d * 32];
        Bkv[lt * 256 + c] = s * scale;
        return;
    }
    if (f >= 16384) return;
    int j = f & 7, l = (f >> 3) & 63, t = (f >> 9) & 7, sb = f >> 12;
    int k = sb * 32 + (l >> 4) * 8 + j;
    int n = t * 16 + (l & 15);
    float val;
    if (idx < 6)        val = mlp_in_w[(size_t)idx * 16384 + (size_t)k * 128 + n];
    else if (idx < 10)  val = q_w[(size_t)(idx - 6) * 16384 + (size_t)k * 128 + n];
    else if (idx < 14)  val = a_w[(size_t)(idx - 10) * 16384 + (size_t)k * 128 + n];
    else if (idx == 14) val = mow0[(size_t)k * 128 + n];
    else if (idx == 15) val = mow1[(size_t)k * 128 + n];
    else if (idx < 24) {                  // folded k'/v' weights
        int u = idx - 16, lt = u >> 1, sec = u & 1;
        int h = n >> 5, e = n & 31;
        const float* W = sec ? vw : kw;
        const float* R = sec ? mrel : arel;
        float scale = sec ? 1.f : prel[lt * 4 + h] * 0.17677669529663687f;
        const float* rp = R + (size_t)(lt * 4 + h) * 1024 + e;
        const float* wp = W + (size_t)lt * 16384 + (size_t)k * 128 + h * 32;
        float s = 0.f;
        #pragma unroll 8
        for (int d = 0; d < 32; ++d) s += wp[d] * rp[(size_t)d * 32];
        val = s * scale;
    } else val = (n < 2) ? mow2[(size_t)k * 2 + n] : 0.f;   // padded w2 unit
    Wswz[(size_t)idx * 16384 + f] = f2bf(val);
}

// ---------------------------------------------------------------- one 16x128 unit pass from LDS-staged B
__device__ __forceinline__ void unit_ldst(const short8 av[4], const unsigned short* __restrict__ Bst,
                                          int lane, float4v acc[8]) {
    #pragma unroll
    for (int t = 0; t < 8; ++t) acc[t] = (float4v){0.f, 0.f, 0.f, 0.f};
    #pragma unroll
    for (int s = 0; s < 4; ++s)
        #pragma unroll
        for (int t = 0; t < 8; ++t) {
            short8 bv = *(const short8*)&Bst[(s * 8 + t) * 512 + lane * 8];
            acc[t] = __builtin_amdgcn_mfma_f32_16x16x32_bf16(av[s], bv, acc[t], 0, 0, 0);
        }
}

// ---------------------------------------------------------------- fused input MLP (3 layers) + layer-0 QKV; prefetch-pipelined staging
__global__ __launch_bounds__(256) void k_mlp3qkv(
    const float* __restrict__ Xa, const float* __restrict__ Xb,
    const unsigned short* __restrict__ Wswz, const float* __restrict__ mlp_in_b,
    const float* __restrict__ q_b, const float* __restrict__ Bkv,
    unsigned short* __restrict__ curS, unsigned short* __restrict__ Qs,
    unsigned short* __restrict__ KVs, int NT, int Nv, int Bv) {
    __shared__ unsigned short Bst[16384];
    __shared__ unsigned short tr[4][16][136];
    const int tid = threadIdx.x;
    const int lane = tid & 63, wave = tid >> 6;
    const int quad = lane >> 4, mrow = lane & 15;
    int bx = blockIdx.x;
    int base, end, type;
    if (bx < Bv) { base = bx * 64; end = Nv; type = 0; }
    else         { base = Nv + (bx - Bv) * 64; end = NT; type = 1; }
    const int mbase = base + wave * 16;
    int r0 = mbase + mrow; if (r0 >= end) r0 = end - 1;
    const bool rok = (mbase + mrow) < end;

    const int un[6] = { type * 3, type * 3 + 1, type * 3 + 2,
                        6 + type, 16 + type * 2, 17 + type * 2 };
    uint4 pf[8];
    auto preload = [&](int u) {
        const uint4* src = (const uint4*)(Wswz + (size_t)u * 16384);
        #pragma unroll
        for (int k = 0; k < 8; ++k) pf[k] = src[tid + k * 256];
    };
    auto commit = [&]() {
        #pragma unroll
        for (int k = 0; k < 8; ++k) ((uint4*)Bst)[tid + k * 256] = pf[k];
    };
    auto trwrite = [&](float4v* acc, const float* b, bool relu) {
        #pragma unroll
        for (int t = 0; t < 8; ++t) {
            int col = t * 16 + mrow;
            float bb = b[col];
            #pragma unroll
            for (int r = 0; r < 4; ++r) {
                float v = acc[t][r] + bb;
                if (relu) v = fmaxf(v, 0.f);
                tr[wave][quad * 4 + r][col] = f2bf(v);
            }
        }
    };
    auto vecstore = [&](unsigned short* C, int ldC, int cb) {
        if (rok) {
            #pragma unroll
            for (int s = 0; s < 4; ++s) {
                uint4 v = *(const uint4*)&tr[wave][mrow][s * 32 + quad * 8];
                *(uint4*)(C + (size_t)r0 * ldC + cb + quad * 8 + s * 32) = v;
            }
        }
    };

    // A fragments from fp32 input
    short8 av[4];
    {
        const float* ap = (type == 0 ? Xa + (size_t)r0 * 128
                                     : Xb + (size_t)(r0 - Nv) * 128) + quad * 8;
        #pragma unroll
        for (int s = 0; s < 4; ++s) {
            float4 f0 = *(const float4*)(ap + s * 32);
            float4 f1 = *(const float4*)(ap + s * 32 + 4);
            short8 a;
            a[0] = (short)f2bf(f0.x); a[1] = (short)f2bf(f0.y);
            a[2] = (short)f2bf(f0.z); a[3] = (short)f2bf(f0.w);
            a[4] = (short)f2bf(f1.x); a[5] = (short)f2bf(f1.y);
            a[6] = (short)f2bf(f1.z); a[7] = (short)f2bf(f1.w);
            av[s] = a;
        }
    }
    const float* bs = mlp_in_b + type * 384;
    preload(un[0]);
    #pragma unroll
    for (int ui = 0; ui < 6; ++ui) {
        __syncthreads();
        commit();
        if (ui < 5) preload(un[ui + 1]);
        __syncthreads();
        float4v acc[8];
        unit_ldst(av, Bst, lane, acc);
        if (ui < 3) {
            trwrite(acc, bs + ui * 128, ui < 2);
            #pragma unroll
            for (int s = 0; s < 4; ++s)
                av[s] = *(const short8*)&tr[wave][mrow][s * 32 + quad * 8];
            if (ui == 2) vecstore(curS, 128, 0);
        } else if (ui == 3) {
            trwrite(acc, q_b + type * 128, false);
            vecstore(Qs, 128, 0);
        } else if (ui == 4) {
            trwrite(acc, Bkv + type * 256, false);
            vecstore(KVs, 256, 0);
        } else {
            trwrite(acc, Bkv + type * 256 + 128, false);
            vecstore(KVs, 256, 128);
        }
    }
}

// ---------------------------------------------------------------- fused alin(0) gated update + QKV(1); prefetch-pipelined
__global__ __launch_bounds__(256) void k_alinqkv(
    const unsigned short* __restrict__ Aagg, const unsigned short* __restrict__ Wswz,
    const float* __restrict__ a_b, const float* __restrict__ skipP,
    const float* __restrict__ q_b, const float* __restrict__ Bkv,
    unsigned short* __restrict__ curS, unsigned short* __restrict__ Qs,
    unsigned short* __restrict__ KVs, int NT, int Nv, int Bv) {
    __shared__ unsigned short Bst[16384];
    __shared__ unsigned short tr[4][16][136];
    const int tid = threadIdx.x;
    const int lane = tid & 63, wave = tid >> 6;
    const int quad = lane >> 4, mrow = lane & 15;
    int bx = blockIdx.x;
    int base, end, type;
    if (bx < Bv) { base = bx * 64; end = Nv; type = 0; }
    else         { base = Nv + (bx - Bv) * 64; end = NT; type = 1; }
    const int mbase = base + wave * 16;
    int r0 = mbase + mrow; if (r0 >= end) r0 = end - 1;
    const bool rok = (mbase + mrow) < end;
    const int ltA = type, ltQ = 2 + type;
    const int un[4] = { 10 + ltA, 6 + ltQ, 16 + ltQ * 2, 17 + ltQ * 2 };

    uint4 pf[8];
    auto preload = [&](int u) {
        const uint4* src = (const uint4*)(Wswz + (size_t)u * 16384);
        #pragma unroll
        for (int k = 0; k < 8; ++k) pf[k] = src[tid + k * 256];
    };
    auto commit = [&]() {
        #pragma unroll
        for (int k = 0; k < 8; ++k) ((uint4*)Bst)[tid + k * 256] = pf[k];
    };
    auto trwrite = [&](float4v* acc, const float* b) {
        #pragma unroll
        for (int t = 0; t < 8; ++t) {
            int col = t * 16 + mrow;
            float bb = b[col];
            #pragma unroll
            for (int r = 0; r < 4; ++r)
                tr[wave][quad * 4 + r][col] = f2bf(acc[t][r] + bb);
        }
    };
    auto vecstore = [&](unsigned short* C, int ldC, int cb) {
        if (rok) {
            #pragma unroll
            for (int s = 0; s < 4; ++s) {
                uint4 v = *(const uint4*)&tr[wave][mrow][s * 32 + quad * 8];
                *(uint4*)(C + (size_t)r0 * ldC + cb + quad * 8 + s * 32) = v;
            }
        }
    };

    short8 av[4];
    {
        const unsigned short* ap = Aagg + (size_t)r0 * 128 + quad * 8;
        #pragma unroll
        for (int s = 0; s < 4; ++s) av[s] = *(const short8*)(ap + s * 32);
    }
    preload(un[0]);
    #pragma unroll
    for (int ui = 0; ui < 4; ++ui) {
        __syncthreads();
        commit();
        if (ui < 3) preload(un[ui + 1]);
        __syncthreads();
        float4v acc[8];
        unit_ldst(av, Bst, lane, acc);
        if (ui == 0) {
            trwrite(acc, a_b + ltA * 128);
            float gg = 1.f / (1.f + __expf(-skipP[ltA]));
            float2v g2 = {gg, gg}, og2 = {1.f - gg, 1.f - gg};
            #pragma unroll
            for (int s = 0; s < 4; ++s) {
                short8 nv = *(const short8*)&tr[wave][mrow][s * 32 + quad * 8];
                uint4 nu = *(uint4*)&nv;
                uint4 ou = *(const uint4*)(curS + (size_t)r0 * 128 + quad * 8 + s * 32);
                uint4 res;
                res.x = gate_pack(nu.x, ou.x, g2, og2);
                res.y = gate_pack(nu.y, ou.y, g2, og2);
                res.z = gate_pack(nu.z, ou.z, g2, og2);
                res.w = gate_pack(nu.w, ou.w, g2, og2);
                if (rok) *(uint4*)(curS + (size_t)r0 * 128 + quad * 8 + s * 32) = res;
                av[s] = *(short8*)&res;
            }
        } else if (ui == 1) {
            trwrite(acc, q_b + ltQ * 128);
            vecstore(Qs, 128, 0);
        } else if (ui == 2) {
            trwrite(acc, Bkv + ltQ * 256);
            vecstore(KVs, 256, 0);
        } else {
            trwrite(acc, Bkv + ltQ * 256 + 128);
            vecstore(KVs, 256, 128);
        }
    }
}

// ---------------------------------------------------------------- fused alin(1,var) + head + pool; prefetch-pipelined
__global__ __launch_bounds__(256) void k_alinhead(
    const unsigned short* __restrict__ Aagg, const unsigned short* __restrict__ Wswz,
    const float* __restrict__ a_b, const float* __restrict__ skipP,
    const unsigned short* __restrict__ curS,
    const float* __restrict__ mob0, const float* __restrict__ mob1,
    const float* __restrict__ mob2, const int* __restrict__ batch,
    int N, int G, float* __restrict__ gsum, float* __restrict__ gcnt) {
    __shared__ unsigned short Bst[16384];
    __shared__ unsigned short tr[4][16][136];
    __shared__ float sb[64][3];
    const int tid = threadIdx.x;
    const int lane = tid & 63, wave = tid >> 6;
    const int quad = lane >> 4, mrow = lane & 15;
    for (int i = tid; i < 192; i += 256) ((float*)sb)[i] = 0.f;
    const int base = blockIdx.x * 64;
    const int mbase = base + wave * 16;
    int r0 = mbase + mrow; if (r0 >= N) r0 = N - 1;
    const int bmin = batch[base < N ? base : N - 1];
    const int un[4] = { 12, 14, 15, 24 };

    uint4 pf[8];
    auto preload = [&](int u) {
        const uint4* src = (const uint4*)(Wswz + (size_t)u * 16384);
        #pragma unroll
        for (int k = 0; k < 8; ++k) pf[k] = src[tid + k * 256];
    };
    auto commit = [&]() {
        #pragma unroll
        for (int k = 0; k < 8; ++k) ((uint4*)Bst)[tid + k * 256] = pf[k];
    };

    short8 av[4];
    {
        const unsigned short* ap = Aagg + (size_t)r0 * 128 + quad * 8;
        #pragma unroll
        for (int s = 0; s < 4; ++s) av[s] = *(const short8*)(ap + s * 32);
    }
    preload(un[0]);
    #pragma unroll
    for (int ui = 0; ui < 4; ++ui) {
        __syncthreads();
        commit();
        if (ui < 3) preload(un[ui + 1]);
        __syncthreads();
        if (ui < 3) {
            float4v acc[8];
            unit_ldst(av, Bst, lane, acc);
            const float* b = (ui == 0) ? (a_b + 2 * 128) : (ui == 1 ? mob0 : mob1);
            #pragma unroll
            for (int t = 0; t < 8; ++t) {
                int col = t * 16 + mrow;
                float bb = b[col];
                #pragma unroll
                for (int r = 0; r < 4; ++r) {
                    float v = acc[t][r] + bb;
                    if (ui > 0) v = fmaxf(v, 0.f);
                    tr[wave][quad * 4 + r][col] = f2bf(v);
                }
            }
            if (ui == 0) {
                float gg = 1.f / (1.f + __expf(-skipP[2]));
                float2v g2 = {gg, gg}, og2 = {1.f - gg, 1.f - gg};
                #pragma unroll
                for (int s = 0; s < 4; ++s) {
                    short8 nv = *(const short8*)&tr[wave][mrow][s * 32 + quad * 8];
                    uint4 nu = *(uint4*)&nv;
                    uint4 ou = *(const uint4*)(curS + (size_t)r0 * 128 + quad * 8 + s * 32);
                    uint4 res;
                    res.x = gate_pack(nu.x, ou.x, g2, og2);
                    res.y = gate_pack(nu.y, ou.y, g2, og2);
                    res.z = gate_pack(nu.z, ou.z, g2, og2);
                    res.w = gate_pack(nu.w, ou.w, g2, og2);
                    av[s] = *(short8*)&res;
                }
            } else {
                #pragma unroll
                for (int s = 0; s < 4; ++s)
                    av[s] = *(const short8*)&tr[wave][mrow][s * 32 + quad * 8];
            }
        } else {
            // logits via padded unit 24 (only t=0 column block non-zero)
            float4v lg = (float4v){0.f, 0.f, 0.f, 0.f};
            #pragma unroll
            for (int s = 0; s < 4; ++s) {
                short8 bv = *(const short8*)&Bst[(s * 8) * 512 + lane * 8];
                lg = __builtin_amdgcn_mfma_f32_16x16x32_bf16(av[s], bv, lg, 0, 0, 0);
            }
            float4v lgo;
            #pragma unroll
            for (int r = 0; r < 4; ++r) lgo[r] = __shfl_xor(lg[r], 1);
            if (mrow == 0) {
                #pragma unroll
                for (int r = 0; r < 4; ++r) {
                    int row = mbase + quad * 4 + r;
                    if (row < N) {
                        float l0 = lg[r] + mob2[0];
                        float l1 = lgo[r] + mob2[1];
                        float mm = fmaxf(l0, l1);
                        float e0 = __expf(l0 - mm), e1 = __expf(l1 - mm);
                        float inv = 1.f / (e0 + e1);
                        int b = batch[row];
                        int rel = b - bmin;
                        if (rel >= 0 && rel < 64) {
                            atomicAdd(&sb[rel][0], e0 * inv);
                            atomicAdd(&sb[rel][1], e1 * inv);
                            atomicAdd(&sb[rel][2], 1.f);
                        } else {
                            atomicAdd(&gsum[b * 2 + 0], e0 * inv);
                            atomicAdd(&gsum[b * 2 + 1], e1 * inv);
                            atomicAdd(&gcnt[b], 1.f);
                        }
                    }
                }
            }
        }
    }
    __syncthreads();
    for (int i = tid; i < 64; i += 256) {
        float c = sb[i][2];
        if (c != 0.f && bmin + i < G) {
            atomicAdd(&gsum[(bmin + i) * 2 + 0], sb[i][0]);
            atomicAdd(&gsum[(bmin + i) * 2 + 1], sb[i][1]);
            atomicAdd(&gcnt[bmin + i], c);
        }
    }
}

// ---------------------------------------------------------------- combined CSR build
__global__ void k_hist2(const int* __restrict__ evc, const int* __restrict__ ecv, int E,
                        int* __restrict__ deg, int Nv) {
    int e = blockIdx.x * 256 + threadIdx.x;
    if (e >= E) return;
    if (blockIdx.y == 0) atomicAdd(&deg[Nv + evc[E + e]], 1);
    else                 atomicAdd(&deg[ecv[E + e]], 1);
}
__global__ void k_scan_block(const int* __restrict__ deg, int n, int* __restrict__ off,
                             int* __restrict__ partials) {
    __shared__ int s[256];
    int i = blockIdx.x * 256 + threadIdx.x;
    s[threadIdx.x] = (i < n) ? deg[i] : 0;
    __syncthreads();
    for (int d = 1; d < 256; d <<= 1) {
        int t = (threadIdx.x >= d) ? s[threadIdx.x - d] : 0;
        __syncthreads();
        s[threadIdx.x] += t;
        __syncthreads();
    }
    if (i < n) off[i + 1] = s[threadIdx.x];
    if (threadIdx.x == 255) partials[blockIdx.x] = s[255];
}
__global__ void k_scan_partials(int* __restrict__ partials, int nb) {
    __shared__ int s[512];
    s[threadIdx.x] = (threadIdx.x < nb) ? partials[threadIdx.x] : 0;
    __syncthreads();
    for (int d = 1; d < 512; d <<= 1) {
        int t = (threadIdx.x >= d) ? s[threadIdx.x - d] : 0;
        __syncthreads();
        s[threadIdx.x] += t;
        __syncthreads();
    }
    if (threadIdx.x < nb) partials[threadIdx.x] = s[threadIdx.x];
}
__global__ void k_scan_add(int* __restrict__ off, int* __restrict__ cur,
                           const int* __restrict__ partials, int n) {
    int i = blockIdx.x * 256 + threadIdx.x;
    if (i == 0) { off[0] = 0; cur[0] = 0; }
    if (i < n) {
        int b = i >> 8;
        int v = off[i + 1] + ((b > 0) ? partials[b - 1] : 0);
        off[i + 1] = v;
        cur[i + 1] = v;
    }
}
__global__ void k_scatter2(const int* __restrict__ evc, const int* __restrict__ ecv, int E,
                           int* __restrict__ cur, int Nv, int* __restrict__ srcAll) {
    int e = blockIdx.x * 256 + threadIdx.x;
    if (e >= E) return;
    if (blockIdx.y == 0) {
        int d = Nv + evc[E + e];
        int pos = atomicAdd(&cur[d], 1);
        srcAll[pos] = evc[e];
    } else {
        int d = ecv[E + e];
        int pos = atomicAdd(&cur[d], 1);
        srcAll[pos] = Nv + ecv[e];
    }
}

// ---------------------------------------------------------------- fused attention: 4 edges/wave, dot2 + vectorized out store
__global__ __launch_bounds__(256) void k_agg(
    const unsigned short* __restrict__ Q, const unsigned short* __restrict__ KV,
    const int* __restrict__ off, const int* __restrict__ csrc,
    unsigned short* __restrict__ out, int NT) {
    int dst = blockIdx.x * 4 + (threadIdx.x >> 6);
    int lane = threadIdx.x & 63;
    if (dst >= NT) return;
    const int g = lane >> 4, w = lane & 15;
    int2 se = *(const int2*)(off + dst);
    int s0 = se.x, s1 = se.y;
    uint4 qr = *(const uint4*)(Q + (size_t)dst * 128 + w * 8);
    float2v a0 = {0.f, 0.f}, a1 = {0.f, 0.f}, a2 = {0.f, 0.f}, a3 = {0.f, 0.f};
    float den = 0.f;
    int j = s0 + g;
    uint4 kr = {0, 0, 0, 0}, vr = {0, 0, 0, 0};
    bool have = j < s1;
    if (have) {
        const unsigned short* kv = KV + (size_t)csrc[j] * 256 + w * 8;
        kr = *(const uint4*)kv;
        vr = *(const uint4*)(kv + 128);
    }
    while (have) {
        int jn = j + 4;
        bool haveN = jn < s1;
        uint4 krn = kr, vrn = vr;
        if (haveN) {
            const unsigned short* kv = KV + (size_t)csrc[jn] * 256 + w * 8;
            krn = *(const uint4*)kv;
            vrn = *(const uint4*)(kv + 128);
        }
        float t = dot2bf(kr.x, qr.x, 0.f);
        t = dot2bf(kr.y, qr.y, t);
        t = dot2bf(kr.z, qr.z, t);
        t = dot2bf(kr.w, qr.w, t);
        t += __shfl_xor(t, 1);
        t += __shfl_xor(t, 2);
        t = fminf(fmaxf(t, -30.f), 30.f);
        float p = __expf(t);
        den += p;
        float2v pv = {p, p};
        a0 += pv * (float2v){bf2f_lo(vr.x), bf2f_hi(vr.x)};
        a1 += pv * (float2v){bf2f_lo(vr.y), bf2f_hi(vr.y)};
        a2 += pv * (float2v){bf2f_lo(vr.z), bf2f_hi(vr.z)};
        a3 += pv * (float2v){bf2f_lo(vr.w), bf2f_hi(vr.w)};
        kr = krn; vr = vrn; j = jn; have = haveN;
    }
    den += __shfl_xor(den, 16); den += __shfl_xor(den, 32);
    a0.x += __shfl_xor(a0.x, 16); a0.x += __shfl_xor(a0.x, 32);
    a0.y += __shfl_xor(a0.y, 16); a0.y += __shfl_xor(a0.y, 32);
    a1.x += __shfl_xor(a1.x, 16); a1.x += __shfl_xor(a1.x, 32);
    a1.y += __shfl_xor(a1.y, 16); a1.y += __shfl_xor(a1.y, 32);
    a2.x += __shfl_xor(a2.x, 16); a2.x += __shfl_xor(a2.x, 32);
    a2.y += __shfl_xor(a2.y, 16); a2.y += __shfl_xor(a2.y, 32);
    a3.x += __shfl_xor(a3.x, 16); a3.x += __shfl_xor(a3.x, 32);
    a3.y += __shfl_xor(a3.y, 16); a3.y += __shfl_xor(a3.y, 32);
    if (g == 0) {
        float inv = (s1 > s0) ? 1.f / den : 0.f;
        uint4 o;
        o.x = pk2(geluf(a0.x * inv), geluf(a0.y * inv));
        o.y = pk2(geluf(a1.x * inv), geluf(a1.y * inv));
        o.z = pk2(geluf(a2.x * inv), geluf(a2.y * inv));
        o.w = pk2(geluf(a3.x * inv), geluf(a3.y * inv));
        *(uint4*)(out + (size_t)dst * 128 + w * 8) = o;
    }
}

// ---------------------------------------------------------------- finalize
__global__ void k_finalize(const float* __restrict__ gsum, const float* __restrict__ gcnt,
                           float* __restrict__ out, int n) {
    int i = blockIdx.x * 256 + threadIdx.x;
    if (i < n) out[i] = gsum[i] / fmaxf(gcnt[i >> 1], 1.f);
}

// ---------------------------------------------------------------- host
extern "C" void kernel_launch(void* const* d_in, const int* in_sizes, int n_in,
                              void* d_out, int out_size, void* d_ws, size_t ws_size,
                              hipStream_t stream) {
    const float* x_var    = (const float*)d_in[0];
    const float* x_con    = (const float*)d_in[1];
    const float* mlp_in_w = (const float*)d_in[2];
    const float* mlp_in_b = (const float*)d_in[3];
    const float* mow0 = (const float*)d_in[4];
    const float* mob0 = (const float*)d_in[5];
    const float* mow1 = (const float*)d_in[6];
    const float* mob1 = (const float*)d_in[7];
    const float* mow2 = (const float*)d_in[8];
    const float* mob2 = (const float*)d_in[9];
    const float* k_w  = (const float*)d_in[10];
    const float* k_b  = (const float*)d_in[11];
    const float* q_w  = (const float*)d_in[12];
    const float* q_b  = (const float*)d_in[13];
    const float* v_w  = (const float*)d_in[14];
    const float* v_b  = (const float*)d_in[15];
    const float* a_w  = (const float*)d_in[16];
    const float* a_b  = (const float*)d_in[17];
    const float* skipP = (const float*)d_in[18];
    const float* a_rel = (const float*)d_in[19];
    const float* m_rel = (const float*)d_in[20];
    const float* p_rel = (const float*)d_in[21];
    const int* edge_vc = (const int*)d_in[22];
    const int* edge_cv = (const int*)d_in[23];
    const int* batch   = (const int*)d_in[24];

    const int Nv = in_sizes[0] / 128;
    const int Nc = in_sizes[1] / 128;
    const int E  = in_sizes[22] / 2;
    const int G  = out_size / 2;
    const int NT = Nv + Nc;

    // ---- workspace layout
    float* fbase = (float*)d_ws;
    size_t fo = 0;
    auto falloc = [&](size_t n) { float* p = fbase + fo; fo += n; return p; };
    float* Bkv  = falloc(4 * 256);
    float* gsum = falloc((size_t)G * 2);
    float* gcnt = falloc((size_t)G);

    unsigned short* bbase = (unsigned short*)(fbase + fo);
    size_t bo = 0;
    auto balloc = [&](size_t n) { unsigned short* p = bbase + bo; bo += n; return p; };
    unsigned short* Wswz = balloc((size_t)25 * 16384);
    unsigned short* curS = balloc((size_t)NT * 128);
    unsigned short* Qs   = balloc((size_t)NT * 128);
    unsigned short* KVs  = balloc((size_t)NT * 256);

    int* ibase = (int*)(bbase + bo);
    size_t io = 0;
    auto ialloc = [&](size_t n) { int* p = ibase + io; io += n; return p; };
    int* offAll = ialloc((size_t)NT + 1);
    int* curAll = ialloc((size_t)NT + 1);
    int* srcAll = ialloc((size_t)E * 2);
    int* deg    = ialloc((size_t)NT);
    int* partials = ialloc(512);

    size_t need = (char*)(ibase + io) - (char*)d_ws;
    if (need > ws_size) return;

    const int eb  = (E + 255) / 256;
    const int nzb = (NT + 255) / 256;
    const int Bv  = (Nv + 63) / 64;
    const int Bc  = (Nc + 63) / 64;

    // ---- combined CSR build
    k_zero<<<nzb, 256, 0, stream>>>(deg, NT);
    k_hist2<<<dim3(eb, 2), 256, 0, stream>>>(edge_vc, edge_cv, E, deg, Nv);
    k_scan_block<<<nzb, 256, 0, stream>>>(deg, NT, offAll, partials);
    k_scan_partials<<<1, 512, 0, stream>>>(partials, nzb);
    k_scan_add<<<nzb, 256, 0, stream>>>(offAll, curAll, partials, NT);
    k_scatter2<<<dim3(eb, 2), 256, 0, stream>>>(edge_vc, edge_cv, E, curAll, Nv, srcAll);

    // ---- weight swizzle (rel-fold inline) + gsum zero
    k_swz<<<dim3(64, 26), 256, 0, stream>>>(mlp_in_w, q_w, a_w, mow0, mow1, mow2,
                                            k_w, k_b, v_w, v_b, a_rel, m_rel, p_rel,
                                            Wswz, Bkv);
    k_zero<<<(G * 3 + 255) / 256, 256, 0, stream>>>((int*)gsum, G * 3);

    // ---- fused pipeline (type-pure 64-row blocks, LDS-staged weights, vec stores)
    k_mlp3qkv<<<Bv + Bc, 256, 0, stream>>>(x_var, x_con, Wswz, mlp_in_b, q_b, Bkv,
                                           curS, Qs, KVs, NT, Nv, Bv);
    k_agg<<<(NT + 3) / 4, 256, 0, stream>>>(Qs, KVs, offAll, srcAll, Qs, NT);
    k_alinqkv<<<Bv + Bc, 256, 0, stream>>>(Qs, Wswz, a_b, skipP, q_b, Bkv,
                                           curS, Qs, KVs, NT, Nv, Bv);
    k_agg<<<(NT + 3) / 4, 256, 0, stream>>>(Qs, KVs, offAll, srcAll, Qs, NT);
    k_alinhead<<<Bv, 256, 0, stream>>>(Qs, Wswz, a_b, skipP, curS,
                                       mob0, mob1, mob2, batch, Nv, G, gsum, gcnt);
    k_finalize<<<(G * 2 + 255) / 256, 256, 0, stream>>>(gsum, gcnt, (float*)d_out, G * 2);
}

// Round 11
// 504.078 us; speedup vs baseline: 1.2074x; 1.2074x over previous
//
#include <hip/hip_runtime.h>
#include <cstddef>
#include <cstdint>

typedef __attribute__((ext_vector_type(8))) short short8;
typedef __attribute__((ext_vector_type(4))) float float4v;
typedef __attribute__((ext_vector_type(2))) float float2v;
typedef __attribute__((ext_vector_type(2))) __bf16 bf162;

// ---------------------------------------------------------------- bf16 helpers
__device__ __forceinline__ float bf2f_lo(unsigned int u) {
    union { unsigned int i; float f; } v; v.i = u << 16; return v.f;
}
__device__ __forceinline__ float bf2f_hi(unsigned int u) {
    union { unsigned int i; float f; } v; v.i = u & 0xFFFF0000u; return v.f;
}
__device__ __forceinline__ unsigned short f2bf(float f) {
    union { float f; unsigned int i; } v; v.f = f;
    unsigned int x = v.i;
    unsigned int r = (x + 0x7FFFu + ((x >> 16) & 1u)) >> 16;
    return (unsigned short)r;
}
__device__ __forceinline__ unsigned int pk2(float lo, float hi) {
    return (unsigned int)f2bf(lo) | ((unsigned int)f2bf(hi) << 16);
}
__device__ __forceinline__ float geluf(float x) {
    return 0.5f * x * (1.0f + erff(x * 0.70710678118654752f));
}
__device__ __forceinline__ float dot2bf(unsigned int a, unsigned int b, float c) {
#if defined(__has_builtin) && __has_builtin(__builtin_amdgcn_fdot2_f32_bf16)
    union U { unsigned int u; bf162 v; };
    U ua, ub; ua.u = a; ub.u = b;
    return __builtin_amdgcn_fdot2_f32_bf16(ua.v, ub.v, c, false);
#else
    return c + bf2f_lo(a) * bf2f_lo(b) + bf2f_hi(a) * bf2f_hi(b);
#endif
}
__device__ __forceinline__ unsigned int gate_pack(unsigned int nu, unsigned int ou,
                                                  float2v g2, float2v og2) {
    float2v n = {bf2f_lo(nu), bf2f_hi(nu)};
    float2v o = {bf2f_lo(ou), bf2f_hi(ou)};
    float2v r = n * g2 + o * og2;
    return pk2(r.x, r.y);
}

// ---------------------------------------------------------------- zero fill
__global__ void k_zero(int* __restrict__ p, int n) {
    int i = blockIdx.x * 256 + threadIdx.x;
    if (i < n) p[i] = 0;
}

// ---------------------------------------------------------------- swizzle weights into MFMA B-fragment order (bf16), 25 units
__global__ void k_swz(const float* __restrict__ mlp_in_w, const float* __restrict__ q_w,
                      const float* __restrict__ a_w, const float* __restrict__ mow0,
                      const float* __restrict__ mow1, const float* __restrict__ mow2,
                      const float* __restrict__ kw, const float* __restrict__ kb,
                      const float* __restrict__ vw, const float* __restrict__ vb,
                      const float* __restrict__ arel, const float* __restrict__ mrel,
                      const float* __restrict__ prel,
                      unsigned short* __restrict__ Wswz, float* __restrict__ Bkv) {
    int idx = blockIdx.y;
    int f = blockIdx.x * 256 + threadIdx.x;
    if (idx == 25) {                      // bias fold for k'/v'
        if (f >= 1024) return;
        int lt = f >> 8, c = f & 255;
        int sec = c >> 7, cc = c & 127, h = cc >> 5, e = cc & 31;
        const float* B = sec ? vb : kb;
        const float* R = sec ? mrel : arel;
        float scale = sec ? 1.f : prel[lt * 4 + h] * 0.17677669529663687f;
        const float* rp = R + (size_t)(lt * 4 + h) * 1024 + e;
        const float* bp = B + lt * 128 + h * 32;
        float s = 0.f;
        #pragma unroll 8
        for (int d = 0; d < 32; ++d) s += bp[d] * rp[(size_t)d * 32];
        Bkv[lt * 256 + c] = s * scale;
        return;
    }
    if (f >= 16384) return;
    int j = f & 7, l = (f >> 3) & 63, t = (f >> 9) & 7, sb = f >> 12;
    int k = sb * 32 + (l >> 4) * 8 + j;
    int n = t * 16 + (l & 15);
    float val;
    if (idx < 6)        val = mlp_in_w[(size_t)idx * 16384 + (size_t)k * 128 + n];
    else if (idx < 10)  val = q_w[(size_t)(idx - 6) * 16384 + (size_t)k * 128 + n];
    else if (idx < 14)  val = a_w[(size_t)(idx - 10) * 16384 + (size_t)k * 128 + n];
    else if (idx == 14) val = mow0[(size_t)k * 128 + n];
    else if (idx == 15) val = mow1[(size_t)k * 128 + n];
    else if (idx < 24) {                  // folded k'/v' weights
        int u = idx - 16, lt = u >> 1, sec = u & 1;
        int h = n >> 5, e = n & 31;
        const float* W = sec ? vw : kw;
        const float* R = sec ? mrel : arel;
        float scale = sec ? 1.f : prel[lt * 4 + h] * 0.17677669529663687f;
        const float* rp = R + (size_t)(lt * 4 + h) * 1024 + e;
        const float* wp = W + (size_t)lt * 16384 + (size_t)k * 128 + h * 32;
        float s = 0.f;
        #pragma unroll 8
        for (int d = 0; d < 32; ++d) s += wp[d] * rp[(size_t)d * 32];
        val = s * scale;
    } else val = (n < 2) ? mow2[(size_t)k * 2 + n] : 0.f;   // padded w2 unit
    Wswz[(size_t)idx * 16384 + f] = f2bf(val);
}

// ---------------------------------------------------------------- stage one 32 KB B-unit into LDS (all 256 threads)
__device__ __forceinline__ void stageB(const unsigned short* __restrict__ Wu,
                                       unsigned short* __restrict__ Bst, int tid) {
    #pragma unroll
    for (int k = 0; k < 8; ++k)
        ((uint4*)Bst)[tid + k * 256] = ((const uint4*)Wu)[tid + k * 256];
}

// ---------------------------------------------------------------- one 16x128 unit pass from LDS-staged B
__device__ __forceinline__ void unit_ldst(const short8 av[4], const unsigned short* __restrict__ Bst,
                                          int lane, float4v acc[8]) {
    #pragma unroll
    for (int t = 0; t < 8; ++t) acc[t] = (float4v){0.f, 0.f, 0.f, 0.f};
    #pragma unroll
    for (int s = 0; s < 4; ++s)
        #pragma unroll
        for (int t = 0; t < 8; ++t) {
            short8 bv = *(const short8*)&Bst[(s * 8 + t) * 512 + lane * 8];
            acc[t] = __builtin_amdgcn_mfma_f32_16x16x32_bf16(av[s], bv, acc[t], 0, 0, 0);
        }
}

#define TRP 138   // tr row padding (69 words -> ~2-way banks max)

// write MFMA acc tile (C layout) into tr
__device__ __forceinline__ void tr_write(unsigned short (*trw)[TRP], const float4v* acc,
                                         const float* bias, bool relu, int quad, int mrow) {
    #pragma unroll
    for (int t = 0; t < 8; ++t) {
        int col = t * 16 + mrow;
        float bb = bias[col];
        #pragma unroll
        for (int r = 0; r < 4; ++r) {
            float v = acc[t][r] + bb;
            if (relu) v = fmaxf(v, 0.f);
            trw[quad * 4 + r][col] = f2bf(v);
        }
    }
}
// lane-contiguous 16B store of one 16x128 tile from tr
__device__ __forceinline__ void tr_store(const unsigned short (*trw)[TRP],
                                         unsigned short* __restrict__ C, int ldC, int cb,
                                         int mtile, int end, int quad, int mrow) {
    #pragma unroll
    for (int s = 0; s < 4; ++s) {
        int row = mtile + s * 4 + quad;
        uint4 v = *(const uint4*)&trw[s * 4 + quad][mrow * 8];
        if (row < end)
            *(uint4*)(C + (size_t)row * ldC + cb + mrow * 8) = v;
    }
}

// ---------------------------------------------------------------- fused input MLP (3 layers) + layer-0 QKV; 2 tiles/wave
__global__ __launch_bounds__(256) void k_mlp3qkv(
    const float* __restrict__ Xa, const float* __restrict__ Xb,
    const unsigned short* __restrict__ Wswz, const float* __restrict__ mlp_in_b,
    const float* __restrict__ q_b, const float* __restrict__ Bkv,
    unsigned short* __restrict__ curS, unsigned short* __restrict__ Qs,
    unsigned short* __restrict__ KVs, int NT, int Nv, int Bv) {
    __shared__ unsigned short Bst[16384];
    __shared__ unsigned short tr[4][16][TRP];
    const int tid = threadIdx.x;
    const int lane = tid & 63, wave = tid >> 6;
    const int quad = lane >> 4, mrow = lane & 15;
    int bx = blockIdx.x;
    int base, end, type;
    if (bx < Bv) { base = bx * 128; end = Nv; type = 0; }
    else         { base = Nv + (bx - Bv) * 128; end = NT; type = 1; }
    const int mbase = base + wave * 32;

    short8 av[2][4];
    #pragma unroll
    for (int tile = 0; tile < 2; ++tile) {
        int r = mbase + tile * 16 + mrow; if (r >= end) r = end - 1;
        const float* ap = (type == 0 ? Xa + (size_t)r * 128
                                     : Xb + (size_t)(r - Nv) * 128) + quad * 8;
        #pragma unroll
        for (int s = 0; s < 4; ++s) {
            float4 f0 = *(const float4*)(ap + s * 32);
            float4 f1 = *(const float4*)(ap + s * 32 + 4);
            short8 a;
            a[0] = (short)f2bf(f0.x); a[1] = (short)f2bf(f0.y);
            a[2] = (short)f2bf(f0.z); a[3] = (short)f2bf(f0.w);
            a[4] = (short)f2bf(f1.x); a[5] = (short)f2bf(f1.y);
            a[6] = (short)f2bf(f1.z); a[7] = (short)f2bf(f1.w);
            av[tile][s] = a;
        }
    }
    const float* bs = mlp_in_b + type * 384;
    const int un[6] = { type * 3, type * 3 + 1, type * 3 + 2,
                        6 + type, 16 + type * 2, 17 + type * 2 };
    #pragma unroll
    for (int ui = 0; ui < 6; ++ui) {
        __syncthreads();
        stageB(Wswz + (size_t)un[ui] * 16384, Bst, tid);
        __syncthreads();
        #pragma unroll
        for (int tile = 0; tile < 2; ++tile) {
            int mtile = mbase + tile * 16;
            float4v acc[8];
            unit_ldst(av[tile], Bst, lane, acc);
            if (ui < 3) {
                tr_write(tr[wave], acc, bs + ui * 128, ui < 2, quad, mrow);
                #pragma unroll
                for (int s = 0; s < 4; ++s)
                    av[tile][s] = *(const short8*)&tr[wave][mrow][s * 32 + quad * 8];
                if (ui == 2) tr_store(tr[wave], curS, 128, 0, mtile, end, quad, mrow);
            } else if (ui == 3) {
                tr_write(tr[wave], acc, q_b + type * 128, false, quad, mrow);
                tr_store(tr[wave], Qs, 128, 0, mtile, end, quad, mrow);
            } else if (ui == 4) {
                tr_write(tr[wave], acc, Bkv + type * 256, false, quad, mrow);
                tr_store(tr[wave], KVs, 256, 0, mtile, end, quad, mrow);
            } else {
                tr_write(tr[wave], acc, Bkv + type * 256 + 128, false, quad, mrow);
                tr_store(tr[wave], KVs, 256, 128, mtile, end, quad, mrow);
            }
        }
    }
}

// ---------------------------------------------------------------- fused alin(0) gated update + QKV(1); 2 tiles/wave
__global__ __launch_bounds__(256) void k_alinqkv(
    const unsigned short* __restrict__ Aagg, const unsigned short* __restrict__ Wswz,
    const float* __restrict__ a_b, const float* __restrict__ skipP,
    const float* __restrict__ q_b, const float* __restrict__ Bkv,
    unsigned short* __restrict__ curS, unsigned short* __restrict__ Qs,
    unsigned short* __restrict__ KVs, int NT, int Nv, int Bv) {
    __shared__ unsigned short Bst[16384];
    __shared__ unsigned short tr[4][16][TRP];
    const int tid = threadIdx.x;
    const int lane = tid & 63, wave = tid >> 6;
    const int quad = lane >> 4, mrow = lane & 15;
    int bx = blockIdx.x;
    int base, end, type;
    if (bx < Bv) { base = bx * 128; end = Nv; type = 0; }
    else         { base = Nv + (bx - Bv) * 128; end = NT; type = 1; }
    const int mbase = base + wave * 32;
    const int ltA = type, ltQ = 2 + type;
    const int un[4] = { 10 + ltA, 6 + ltQ, 16 + ltQ * 2, 17 + ltQ * 2 };

    short8 av[2][4];
    #pragma unroll
    for (int tile = 0; tile < 2; ++tile) {
        int r = mbase + tile * 16 + mrow; if (r >= end) r = end - 1;
        const unsigned short* ap = Aagg + (size_t)r * 128 + quad * 8;
        #pragma unroll
        for (int s = 0; s < 4; ++s) av[tile][s] = *(const short8*)(ap + s * 32);
    }
    #pragma unroll
    for (int ui = 0; ui < 4; ++ui) {
        __syncthreads();
        stageB(Wswz + (size_t)un[ui] * 16384, Bst, tid);
        __syncthreads();
        #pragma unroll
        for (int tile = 0; tile < 2; ++tile) {
            int mtile = mbase + tile * 16;
            float4v acc[8];
            unit_ldst(av[tile], Bst, lane, acc);
            if (ui == 0) {
                tr_write(tr[wave], acc, a_b + ltA * 128, false, quad, mrow);
                float gg = 1.f / (1.f + __expf(-skipP[ltA]));
                float2v g2 = {gg, gg}, og2 = {1.f - gg, 1.f - gg};
                // blend + store in lane-contiguous mapping, write back to tr
                #pragma unroll
                for (int s = 0; s < 4; ++s) {
                    int row = mtile + s * 4 + quad;
                    int rowc = (row < end) ? row : end - 1;
                    uint4 nu = *(const uint4*)&tr[wave][s * 4 + quad][mrow * 8];
                    uint4 ou = *(const uint4*)(curS + (size_t)rowc * 128 + mrow * 8);
                    uint4 res;
                    res.x = gate_pack(nu.x, ou.x, g2, og2);
                    res.y = gate_pack(nu.y, ou.y, g2, og2);
                    res.z = gate_pack(nu.z, ou.z, g2, og2);
                    res.w = gate_pack(nu.w, ou.w, g2, og2);
                    if (row < end) *(uint4*)(curS + (size_t)row * 128 + mrow * 8) = res;
                    *(uint4*)&tr[wave][s * 4 + quad][mrow * 8] = res;
                }
                #pragma unroll
                for (int s = 0; s < 4; ++s)
                    av[tile][s] = *(const short8*)&tr[wave][mrow][s * 32 + quad * 8];
            } else if (ui == 1) {
                tr_write(tr[wave], acc, q_b + ltQ * 128, false, quad, mrow);
                tr_store(tr[wave], Qs, 128, 0, mtile, end, quad, mrow);
            } else if (ui == 2) {
                tr_write(tr[wave], acc, Bkv + ltQ * 256, false, quad, mrow);
                tr_store(tr[wave], KVs, 256, 0, mtile, end, quad, mrow);
            } else {
                tr_write(tr[wave], acc, Bkv + ltQ * 256 + 128, false, quad, mrow);
                tr_store(tr[wave], KVs, 256, 128, mtile, end, quad, mrow);
            }
        }
    }
}

// ---------------------------------------------------------------- fused alin(1,var) + head + pool; 2 tiles/wave
__global__ __launch_bounds__(256) void k_alinhead(
    const unsigned short* __restrict__ Aagg, const unsigned short* __restrict__ Wswz,
    const float* __restrict__ a_b, const float* __restrict__ skipP,
    const unsigned short* __restrict__ curS,
    const float* __restrict__ mob0, const float* __restrict__ mob1,
    const float* __restrict__ mob2, const int* __restrict__ batch,
    int N, int G, float* __restrict__ gsum, float* __restrict__ gcnt) {
    __shared__ unsigned short Bst[16384];
    __shared__ unsigned short tr[4][16][TRP];
    __shared__ float sb[64][3];
    const int tid = threadIdx.x;
    const int lane = tid & 63, wave = tid >> 6;
    const int quad = lane >> 4, mrow = lane & 15;
    for (int i = tid; i < 192; i += 256) ((float*)sb)[i] = 0.f;
    const int base = blockIdx.x * 128;
    const int mbase = base + wave * 32;
    const int bmin = batch[base < N ? base : N - 1];
    const int un[4] = { 12, 14, 15, 24 };

    short8 av[2][4];
    #pragma unroll
    for (int tile = 0; tile < 2; ++tile) {
        int r = mbase + tile * 16 + mrow; if (r >= N) r = N - 1;
        const unsigned short* ap = Aagg + (size_t)r * 128 + quad * 8;
        #pragma unroll
        for (int s = 0; s < 4; ++s) av[tile][s] = *(const short8*)(ap + s * 32);
    }
    #pragma unroll
    for (int ui = 0; ui < 4; ++ui) {
        __syncthreads();
        stageB(Wswz + (size_t)un[ui] * 16384, Bst, tid);
        __syncthreads();
        #pragma unroll
        for (int tile = 0; tile < 2; ++tile) {
            int mtile = mbase + tile * 16;
            if (ui < 3) {
                float4v acc[8];
                unit_ldst(av[tile], Bst, lane, acc);
                const float* b = (ui == 0) ? (a_b + 2 * 128) : (ui == 1 ? mob0 : mob1);
                tr_write(tr[wave], acc, b, ui > 0, quad, mrow);
                if (ui == 0) {
                    float gg = 1.f / (1.f + __expf(-skipP[2]));
                    float2v g2 = {gg, gg}, og2 = {1.f - gg, 1.f - gg};
                    #pragma unroll
                    for (int s = 0; s < 4; ++s) {
                        int row = mtile + s * 4 + quad;
                        int rowc = (row < N) ? row : N - 1;
                        uint4 nu = *(const uint4*)&tr[wave][s * 4 + quad][mrow * 8];
                        uint4 ou = *(const uint4*)(curS + (size_t)rowc * 128 + mrow * 8);
                        uint4 res;
                        res.x = gate_pack(nu.x, ou.x, g2, og2);
                        res.y = gate_pack(nu.y, ou.y, g2, og2);
                        res.z = gate_pack(nu.z, ou.z, g2, og2);
                        res.w = gate_pack(nu.w, ou.w, g2, og2);
                        *(uint4*)&tr[wave][s * 4 + quad][mrow * 8] = res;
                    }
                }
                #pragma unroll
                for (int s = 0; s < 4; ++s)
                    av[tile][s] = *(const short8*)&tr[wave][mrow][s * 32 + quad * 8];
            } else {
                // logits via padded unit 24 (only t=0 column block non-zero)
                float4v lg = (float4v){0.f, 0.f, 0.f, 0.f};
                #pragma unroll
                for (int s = 0; s < 4; ++s) {
                    short8 bv = *(const short8*)&Bst[(s * 8) * 512 + lane * 8];
                    lg = __builtin_amdgcn_mfma_f32_16x16x32_bf16(av[tile][s], bv, lg, 0, 0, 0);
                }
                float4v lgo;
                #pragma unroll
                for (int r = 0; r < 4; ++r) lgo[r] = __shfl_xor(lg[r], 1);
                if (mrow == 0) {
                    #pragma unroll
                    for (int r = 0; r < 4; ++r) {
                        int row = mtile + quad * 4 + r;
                        if (row < N) {
                            float l0 = lg[r] + mob2[0];
                            float l1 = lgo[r] + mob2[1];
                            float mm = fmaxf(l0, l1);
                            float e0 = __expf(l0 - mm), e1 = __expf(l1 - mm);
                            float inv = 1.f / (e0 + e1);
                            int b = batch[row];
                            int rel = b - bmin;
                            if (rel >= 0 && rel < 64) {
                                atomicAdd(&sb[rel][0], e0 * inv);
                                atomicAdd(&sb[rel][1], e1 * inv);
                                atomicAdd(&sb[rel][2], 1.f);
                            } else {
                                atomicAdd(&gsum[b * 2 + 0], e0 * inv);
                                atomicAdd(&gsum[b * 2 + 1], e1 * inv);
                                atomicAdd(&gcnt[b], 1.f);
                            }
                        }
                    }
                }
            }
        }
    }
    __syncthreads();
    for (int i = tid; i < 64; i += 256) {
        float c = sb[i][2];
        if (c != 0.f && bmin + i < G) {
            atomicAdd(&gsum[(bmin + i) * 2 + 0], sb[i][0]);
            atomicAdd(&gsum[(bmin + i) * 2 + 1], sb[i][1]);
            atomicAdd(&gcnt[bmin + i], c);
        }
    }
}

// ---------------------------------------------------------------- combined CSR build
__global__ void k_hist2(const int* __restrict__ evc, const int* __restrict__ ecv, int E,
                        int* __restrict__ deg, int Nv) {
    int e = blockIdx.x * 256 + threadIdx.x;
    if (e >= E) return;
    if (blockIdx.y == 0) atomicAdd(&deg[Nv + evc[E + e]], 1);
    else                 atomicAdd(&deg[ecv[E + e]], 1);
}
__global__ void k_scan_block(const int* __restrict__ deg, int n, int* __restrict__ off,
                             int* __restrict__ partials) {
    __shared__ int s[256];
    int i = blockIdx.x * 256 + threadIdx.x;
    s[threadIdx.x] = (i < n) ? deg[i] : 0;
    __syncthreads();
    for (int d = 1; d < 256; d <<= 1) {
        int t = (threadIdx.x >= d) ? s[threadIdx.x - d] : 0;
        __syncthreads();
        s[threadIdx.x] += t;
        __syncthreads();
    }
    if (i < n) off[i + 1] = s[threadIdx.x];
    if (threadIdx.x == 255) partials[blockIdx.x] = s[255];
}
__global__ void k_scan_partials(int* __restrict__ partials, int nb) {
    __shared__ int s[512];
    s[threadIdx.x] = (threadIdx.x < nb) ? partials[threadIdx.x] : 0;
    __syncthreads();
    for (int d = 1; d < 512; d <<= 1) {
        int t = (threadIdx.x >= d) ? s[threadIdx.x - d] : 0;
        __syncthreads();
        s[threadIdx.x] += t;
        __syncthreads();
    }
    if (threadIdx.x < nb) partials[threadIdx.x] = s[threadIdx.x];
}
__global__ void k_scan_add(int* __restrict__ off, int* __restrict__ cur,
                           const int* __restrict__ partials, int n) {
    int i = blockIdx.x * 256 + threadIdx.x;
    if (i == 0) { off[0] = 0; cur[0] = 0; }
    if (i < n) {
        int b = i >> 8;
        int v = off[i + 1] + ((b > 0) ? partials[b - 1] : 0);
        off[i + 1] = v;
        cur[i + 1] = v;
    }
}
__global__ void k_scatter2(const int* __restrict__ evc, const int* __restrict__ ecv, int E,
                           int* __restrict__ cur, int Nv, int* __restrict__ srcAll) {
    int e = blockIdx.x * 256 + threadIdx.x;
    if (e >= E) return;
    if (blockIdx.y == 0) {
        int d = Nv + evc[E + e];
        int pos = atomicAdd(&cur[d], 1);
        srcAll[pos] = evc[e];
    } else {
        int d = ecv[E + e];
        int pos = atomicAdd(&cur[d], 1);
        srcAll[pos] = Nv + ecv[e];
    }
}

// ---------------------------------------------------------------- fused attention: 4 edges/wave, dot2 + vectorized out store
__global__ __launch_bounds__(256) void k_agg(
    const unsigned short* __restrict__ Q, const unsigned short* __restrict__ KV,
    const int* __restrict__ off, const int* __restrict__ csrc,
    unsigned short* __restrict__ out, int NT) {
    int dst = blockIdx.x * 4 + (threadIdx.x >> 6);
    int lane = threadIdx.x & 63;
    if (dst >= NT) return;
    const int g = lane >> 4, w = lane & 15;
    int2 se = *(const int2*)(off + dst);
    int s0 = se.x, s1 = se.y;
    uint4 qr = *(const uint4*)(Q + (size_t)dst * 128 + w * 8);
    float2v a0 = {0.f, 0.f}, a1 = {0.f, 0.f}, a2 = {0.f, 0.f}, a3 = {0.f, 0.f};
    float den = 0.f;
    int j = s0 + g;
    uint4 kr = {0, 0, 0, 0}, vr = {0, 0, 0, 0};
    bool have = j < s1;
    if (have) {
        const unsigned short* kv = KV + (size_t)csrc[j] * 256 + w * 8;
        kr = *(const uint4*)kv;
        vr = *(const uint4*)(kv + 128);
    }
    while (have) {
        int jn = j + 4;
        bool haveN = jn < s1;
        uint4 krn = kr, vrn = vr;
        if (haveN) {
            const unsigned short* kv = KV + (size_t)csrc[jn] * 256 + w * 8;
            krn = *(const uint4*)kv;
            vrn = *(const uint4*)(kv + 128);
        }
        float t = dot2bf(kr.x, qr.x, 0.f);
        t = dot2bf(kr.y, qr.y, t);
        t = dot2bf(kr.z, qr.z, t);
        t = dot2bf(kr.w, qr.w, t);
        t += __shfl_xor(t, 1);
        t += __shfl_xor(t, 2);
        t = fminf(fmaxf(t, -30.f), 30.f);
        float p = __expf(t);
        den += p;
        float2v pv = {p, p};
        a0 += pv * (float2v){bf2f_lo(vr.x), bf2f_hi(vr.x)};
        a1 += pv * (float2v){bf2f_lo(vr.y), bf2f_hi(vr.y)};
        a2 += pv * (float2v){bf2f_lo(vr.z), bf2f_hi(vr.z)};
        a3 += pv * (float2v){bf2f_lo(vr.w), bf2f_hi(vr.w)};
        kr = krn; vr = vrn; j = jn; have = haveN;
    }
    den += __shfl_xor(den, 16); den += __shfl_xor(den, 32);
    a0.x += __shfl_xor(a0.x, 16); a0.x += __shfl_xor(a0.x, 32);
    a0.y += __shfl_xor(a0.y, 16); a0.y += __shfl_xor(a0.y, 32);
    a1.x += __shfl_xor(a1.x, 16); a1.x += __shfl_xor(a1.x, 32);
    a1.y += __shfl_xor(a1.y, 16); a1.y += __shfl_xor(a1.y, 32);
    a2.x += __shfl_xor(a2.x, 16); a2.x += __shfl_xor(a2.x, 32);
    a2.y += __shfl_xor(a2.y, 16); a2.y += __shfl_xor(a2.y, 32);
    a3.x += __shfl_xor(a3.x, 16); a3.x += __shfl_xor(a3.x, 32);
    a3.y += __shfl_xor(a3.y, 16); a3.y += __shfl_xor(a3.y, 32);
    if (g == 0) {
        float inv = (s1 > s0) ? 1.f / den : 0.f;
        uint4 o;
        o.x = pk2(geluf(a0.x * inv), geluf(a0.y * inv));
        o.y = pk2(geluf(a1.x * inv), geluf(a1.y * inv));
        o.z = pk2(geluf(a2.x * inv), geluf(a2.y * inv));
        o.w = pk2(geluf(a3.x * inv), geluf(a3.y * inv));
        *(uint4*)(out + (size_t)dst * 128 + w * 8) = o;
    }
}

// ---------------------------------------------------------------- finalize
__global__ void k_finalize(const float* __restrict__ gsum, const float* __restrict__ gcnt,
                           float* __restrict__ out, int n) {
    int i = blockIdx.x * 256 + threadIdx.x;
    if (i < n) out[i] = gsum[i] / fmaxf(gcnt[i >> 1], 1.f);
}

// ---------------------------------------------------------------- host
extern "C" void kernel_launch(void* const* d_in, const int* in_sizes, int n_in,
                              void* d_out, int out_size, void* d_ws, size_t ws_size,
                              hipStream_t stream) {
    const float* x_var    = (const float*)d_in[0];
    const float* x_con    = (const float*)d_in[1];
    const float* mlp_in_w = (const float*)d_in[2];
    const float* mlp_in_b = (const float*)d_in[3];
    const float* mow0 = (const float*)d_in[4];
    const float* mob0 = (const float*)d_in[5];
    const float* mow1 = (const float*)d_in[6];
    const float* mob1 = (const float*)d_in[7];
    const float* mow2 = (const float*)d_in[8];
    const float* mob2 = (const float*)d_in[9];
    const float* k_w  = (const float*)d_in[10];
    const float* k_b  = (const float*)d_in[11];
    const float* q_w  = (const float*)d_in[12];
    const float* q_b  = (const float*)d_in[13];
    const float* v_w  = (const float*)d_in[14];
    const float* v_b  = (const float*)d_in[15];
    const float* a_w  = (const float*)d_in[16];
    const float* a_b  = (const float*)d_in[17];
    const float* skipP = (const float*)d_in[18];
    const float* a_rel = (const float*)d_in[19];
    const float* m_rel = (const float*)d_in[20];
    const float* p_rel = (const float*)d_in[21];
    const int* edge_vc = (const int*)d_in[22];
    const int* edge_cv = (const int*)d_in[23];
    const int* batch   = (const int*)d_in[24];

    const int Nv = in_sizes[0] / 128;
    const int Nc = in_sizes[1] / 128;
    const int E  = in_sizes[22] / 2;
    const int G  = out_size / 2;
    const int NT = Nv + Nc;

    // ---- workspace layout
    float* fbase = (float*)d_ws;
    size_t fo = 0;
    auto falloc = [&](size_t n) { float* p = fbase + fo; fo += n; return p; };
    float* Bkv  = falloc(4 * 256);
    float* gsum = falloc((size_t)G * 2);
    float* gcnt = falloc((size_t)G);

    unsigned short* bbase = (unsigned short*)(fbase + fo);
    size_t bo = 0;
    auto balloc = [&](size_t n) { unsigned short* p = bbase + bo; bo += n; return p; };
    unsigned short* Wswz = balloc((size_t)25 * 16384);
    unsigned short* curS = balloc((size_t)NT * 128);
    unsigned short* Qs   = balloc((size_t)NT * 128);
    unsigned short* KVs  = balloc((size_t)NT * 256);

    int* ibase = (int*)(bbase + bo);
    size_t io = 0;
    auto ialloc = [&](size_t n) { int* p = ibase + io; io += n; return p; };
    int* offAll = ialloc((size_t)NT + 1);
    int* curAll = ialloc((size_t)NT + 1);
    int* srcAll = ialloc((size_t)E * 2);
    int* deg    = ialloc((size_t)NT);
    int* partials = ialloc(512);

    size_t need = (char*)(ibase + io) - (char*)d_ws;
    if (need > ws_size) return;

    const int eb  = (E + 255) / 256;
    const int nzb = (NT + 255) / 256;
    const int Bv  = (Nv + 127) / 128;
    const int Bc  = (Nc + 127) / 128;

    // ---- combined CSR build
    k_zero<<<nzb, 256, 0, stream>>>(deg, NT);
    k_hist2<<<dim3(eb, 2), 256, 0, stream>>>(edge_vc, edge_cv, E, deg, Nv);
    k_scan_block<<<nzb, 256, 0, stream>>>(deg, NT, offAll, partials);
    k_scan_partials<<<1, 512, 0, stream>>>(partials, nzb);
    k_scan_add<<<nzb, 256, 0, stream>>>(offAll, curAll, partials, NT);
    k_scatter2<<<dim3(eb, 2), 256, 0, stream>>>(edge_vc, edge_cv, E, curAll, Nv, srcAll);

    // ---- weight swizzle (rel-fold inline) + gsum zero
    k_swz<<<dim3(64, 26), 256, 0, stream>>>(mlp_in_w, q_w, a_w, mow0, mow1, mow2,
                                            k_w, k_b, v_w, v_b, a_rel, m_rel, p_rel,
                                            Wswz, Bkv);
    k_zero<<<(G * 3 + 255) / 256, 256, 0, stream>>>((int*)gsum, G * 3);

    // ---- fused pipeline (type-pure 128-row blocks, LDS-staged weights, lane-contig stores)
    k_mlp3qkv<<<Bv + Bc, 256, 0, stream>>>(x_var, x_con, Wswz, mlp_in_b, q_b, Bkv,
                                           curS, Qs, KVs, NT, Nv, Bv);
    k_agg<<<(NT + 3) / 4, 256, 0, stream>>>(Qs, KVs, offAll, srcAll, Qs, NT);
    k_alinqkv<<<Bv + Bc, 256, 0, stream>>>(Qs, Wswz, a_b, skipP, q_b, Bkv,
                                           curS, Qs, KVs, NT, Nv, Bv);
    k_agg<<<(NT + 3) / 4, 256, 0, stream>>>(Qs, KVs, offAll, srcAll, Qs, NT);
    k_alinhead<<<Bv, 256, 0, stream>>>(Qs, Wswz, a_b, skipP, curS,
                                       mob0, mob1, mob2, batch, Nv, G, gsum, gcnt);
    k_finalize<<<(G * 2 + 255) / 256, 256, 0, stream>>>(gsum, gcnt, (float*)d_out, G * 2);
}